// Round 14
// baseline (767.125 us; speedup 1.0000x reference)
//
#include <hip/hip_runtime.h>

#define NT     65536
#define NGRID  28
#define NX     19
#define HDIM   20
#define PF     4
#define WARM   64
#define TGB    16             // (t,g) pairs per ax_kernel block

typedef float f2 __attribute__((ext_vector_type(2)));
typedef float f4 __attribute__((ext_vector_type(4)));
typedef unsigned short u16;
typedef u16 u16x4 __attribute__((ext_vector_type(4)));

#if __has_builtin(__builtin_amdgcn_exp2f)
#define EXP2(x) __builtin_amdgcn_exp2f(x)
#else
#define EXP2(x) exp2f(x)
#endif
#define L2E 1.4426950408889634f

__device__ __forceinline__ float frcp(float v) { return __builtin_amdgcn_rcpf(v); }

__device__ __forceinline__ void pk_fma(f2& acc, f2 a, f2 b) {
    asm("v_pk_fma_f32 %0, %1, %2, %0" : "+v"(acc) : "v"(a), "v"(b));
}

// 4-lane (quad) sum via DPP quad_perm butterflies — all lanes get the sum.
__device__ __forceinline__ float quad_sum(float v) {
    float a = v + __builtin_bit_cast(float,
        __builtin_amdgcn_update_dpp(0, __builtin_bit_cast(int, v), 0xB1, 0xF, 0xF, true));
    return a + __builtin_bit_cast(float,
        __builtin_amdgcn_update_dpp(0, __builtin_bit_cast(int, a), 0x4E, 0xF, 0xF, true));
}

// h-part weight of gate row r, output-feedback absorbed:
// wh'[r][k] = W_hh[r][k] + W_ih[r][19]*W_out[k]   (k<20)
__device__ __forceinline__ float whp(const float* W_ih, const float* W_hh,
                                     const float* W_out, int r, int k) {
    if (k >= HDIM) return 0.f;
    return fmaf(W_ih[r * 20 + 19], W_out[k], W_hh[r * 20 + k]);
}

__device__ __forceinline__ float ldax(const u16* p, size_t off) {
    return (float)__builtin_bit_cast(_Float16, p[off]);
}

// ============================================================================
// Phase A: Ax[trel][g][r] = sum_{k<19} W_ih[r][k]*x[aw_base+trel][g][k], f16.
// Pure-throughput; thread = (pair-in-block, 4 rows); 8 B packed stores.
// ============================================================================
__global__ __launch_bounds__(320) void ax_kernel(
    const float* __restrict__ x, const float* __restrict__ W_ih,
    u16* __restrict__ Aws, int aw_base)
{
    __shared__ float xs[TGB * NX];     // 304
    __shared__ float ws[80 * NX];      // 1520
    const int    tid = threadIdx.x;
    const size_t tg0 = (size_t)blockIdx.x * TGB;     // pair index rel to aw_base

    if (tid < TGB * NX) xs[tid] = x[((size_t)aw_base * NGRID) * NX + tg0 * NX + tid];
    for (int i = tid; i < 80 * NX; i += 320) {
        const int r = i / NX, k = i - NX * r;
        ws[i] = W_ih[r * 20 + k];
    }
    __syncthreads();

    const int tl = tid / 20;           // 0..15
    const int r4 = (tid % 20) * 4;     // 0,4,...,76
    const float* xp = &xs[tl * NX];
    float a0 = 0.f, a1 = 0.f, a2 = 0.f, a3 = 0.f;
#pragma unroll
    for (int k = 0; k < NX; ++k) {
        const float xv = xp[k];
        a0 = fmaf(xv, ws[(r4 + 0) * NX + k], a0);
        a1 = fmaf(xv, ws[(r4 + 1) * NX + k], a1);
        a2 = fmaf(xv, ws[(r4 + 2) * NX + k], a2);
        a3 = fmaf(xv, ws[(r4 + 3) * NX + k], a3);
    }
    u16x4 o;
    o.x = __builtin_bit_cast(u16, (_Float16)a0);
    o.y = __builtin_bit_cast(u16, (_Float16)a1);
    o.z = __builtin_bit_cast(u16, (_Float16)a2);
    o.w = __builtin_bit_cast(u16, (_Float16)a3);
    *(u16x4*)&Aws[(tg0 + tl) * 80 + r4] = o;
}

// ============================================================================
// Phase B: h-only recurrence. One wave per (chunk, cell). Lane l owns gate
// row l's h-dot (10 f2 weights); o-rows 64..79 quad-shared over 8-wide
// quarters of padded h + DPP reduce; out row (w_out) quartered the same way.
// Ax streamed from workspace as f16 (2 ushort loads/step, PF-deep pipeline).
// Per-lane weights 36 regs -> total demand ~75, fits the 128-granule: no AGPR
// parking (r5-r12: ~120-reg demand cost ~190 cy/step in v_accvgpr_read copies;
// VOP3P can't source AGPRs — r12 assembler reject) and 16 waves/CU occupancy.
// ============================================================================
__global__ __launch_bounds__(64, 4) void lstm_main_kernel(
    const u16*   __restrict__ Aws,    // ((lead+NTSEG)*NGRID, 80) f16
    const float* __restrict__ W_ih,   // (80, 20) — feedback col only
    const float* __restrict__ W_hh,   // (80, 20)
    const float* __restrict__ b_ih,   // (80,)
    const float* __restrict__ b_hh,   // (80,)
    const float* __restrict__ W_out,  // (1, 20)
    const float* __restrict__ b_out,  // (1,)
    float* __restrict__ out,          // (NT, NGRID)
    int ci0, int chunkSz, int aw_base, int t_hi)
{
    __shared__ __align__(16) float hb[2][32];    // h(20) | 0-pad(12), ping-pong
    __shared__ __align__(16) float gls[20][4];   // activated gates (si,sf,tg,so)

    const int b  = blockIdx.x;
    const int cil = b / NGRID;
    const int g   = b - cil * NGRID;
    const int l  = threadIdx.x;
    const int qd = l >> 2;          // quad 0..15
    const int qi = l & 3;           // lane-in-quad
    const int qb = 8 * qi;          // 8-wide quarter base in padded h

    const int tstart = (ci0 + cil) * chunkSz;
    const int t0     = (tstart == 0) ? 0 : tstart - WARM;

    const int g1 = l / HDIM;        // own row's gate class (0=i,1=f,2=g,3=o)
    const int u1 = l % HDIM;        // own row's unit

    const float bout = b_out[0];

    // own row l: 10 f2 over h[0..19]
    f2 whn[10];
#pragma unroll
    for (int j = 0; j < 10; ++j)
        whn[j] = f2{whp(W_ih, W_hh, W_out, l, 2 * j),
                    whp(W_ih, W_hh, W_out, l, 2 * j + 1)};
    const float bb1 = b_ih[l] + b_hh[l];
    const float bpf = fmaf(W_ih[l * 20 + 19], bout, bb1);
    float bpc = (tstart == 0) ? bb1 : bpf;

    // quad-shared o-row rs = 64+qd: this lane's 8-wide quarter
    const int rs = 64 + qd;
    f2 wsq[4], woq[4];
#pragma unroll
    for (int m = 0; m < 4; ++m) {
        const int k0 = qb + 2 * m, k1 = k0 + 1;
        wsq[m] = f2{whp(W_ih, W_hh, W_out, rs, k0), whp(W_ih, W_hh, W_out, rs, k1)};
        woq[m] = f2{(k0 < HDIM) ? W_out[k0] : 0.f, (k1 < HDIM) ? W_out[k1] : 0.f};
    }
    const float bbs = b_ih[rs] + b_hh[rs];
    const float bsf = fmaf(W_ih[rs * 20 + 19], bout, bbs);
    float bsc = (tstart == 0) ? bbs : bsf;

    // own-row activation (exp2 form): act = A1 + B1 * rcp(1 + exp2(m1*a))
    const float m1 = (g1 == 2) ? (2.f * L2E) : -L2E;
    const float A1 = (g1 == 2) ?  1.f :  0.f;
    const float B1 = (g1 == 2) ? -2.f :  1.f;

    // Ax streams (f16): own row l and shared row 64+qd; base at t0
    const size_t tsa = (size_t)NGRID * 80;
    const u16* axb = Aws + ((size_t)(t0 - aw_base) * NGRID + g) * 80 + l;
    const u16* axs = Aws + ((size_t)(t0 - aw_base) * NGRID + g) * 80 + 64 + qd;
    float ap[PF], as[PF];
#pragma unroll
    for (int p = 0; p < PF; ++p) {
        int tp = t0 + p; if (tp > t_hi) tp = t_hi;
        ap[p] = ldax(axb, (size_t)(tp - t0) * tsa);
        as[p] = ldax(axs, (size_t)(tp - t0) * tsa);
    }

    // prime LDS: h = 0, pads = 0 in both buffers
    if (l < 32) { hb[0][l] = 0.f; hb[1][l] = 0.f; }

    float  c  = 0.f;
    int    px = 0;
    float* op = out + (size_t)tstart * NGRID + g;

#define STEP(T, DO_STORE)                                                      \
    {                                                                          \
        int tf_ = (T) + PF; if (tf_ > t_hi) tf_ = t_hi;                        \
        const float fp_ = ldax(axb, (size_t)(tf_ - t0) * tsa);                 \
        const float fs_ = ldax(axs, (size_t)(tf_ - t0) * tsa);                 \
        /* own row: 5 broadcast b128 reads, 10 pk_fma; Ax+bias ride in acc */  \
        f2 aA = f2{ap[0], bpc}, aB = f2{0.f, 0.f};                             \
        _Pragma("unroll")                                                      \
        for (int ii = 0; ii < 5; ++ii) {                                       \
            const f4 X = ((const f4*)&hb[px][0])[ii];                          \
            pk_fma(aA, f2{X.x, X.y}, whn[2 * ii]);                             \
            pk_fma(aB, f2{X.z, X.w}, whn[2 * ii + 1]);                         \
        }                                                                      \
        /* quad quarters: 2 b128, 4 distinct addrs/wave */                     \
        const f4 Q0 = *(const f4*)&hb[px][qb];                                 \
        const f4 Q1 = *(const f4*)&hb[px][qb + 4];                             \
        f2 sS = f2{0.f, 0.f}, sO = f2{0.f, 0.f};                               \
        pk_fma(sS, f2{Q0.x, Q0.y}, wsq[0]); pk_fma(sO, f2{Q0.x, Q0.y}, woq[0]); \
        pk_fma(sS, f2{Q0.z, Q0.w}, wsq[1]); pk_fma(sO, f2{Q0.z, Q0.w}, woq[1]); \
        pk_fma(sS, f2{Q1.x, Q1.y}, wsq[2]); pk_fma(sO, f2{Q1.x, Q1.y}, woq[2]); \
        pk_fma(sS, f2{Q1.z, Q1.w}, wsq[3]); pk_fma(sO, f2{Q1.z, Q1.w}, woq[3]); \
        const float vs = quad_sum(sS.x + sS.y);                                \
        const float vo = quad_sum(sO.x + sO.y);     /* out_{T-1} - bout */     \
        const float a1 = aA.x + aA.y + aB.x + aB.y;                            \
        const float e1 = EXP2(m1 * a1);                                        \
        gls[u1][g1] = fmaf(B1, frcp(1.f + e1), A1);                            \
        if (qi == 0) gls[4 + qd][3] = frcp(1.f + EXP2(-L2E * (vs + as[0] + bsc))); \
        if (DO_STORE) { if (l == 0) *op = vo + bout; op += NGRID; }            \
        asm volatile("s_waitcnt lgkmcnt(0)" ::: "memory");                     \
        if (l < HDIM) {                              /* state update */        \
            const f4 gv = *(const f4*)&gls[l][0];    /* si, sf, tg, so */      \
            c = fmaf(gv.y, c, gv.x * gv.z);                                    \
            const float ec = EXP2(2.f * L2E * c);                              \
            hb[px ^ 1][l] = gv.w * (1.f - 2.f * frcp(1.f + ec));               \
        }                                                                      \
        _Pragma("unroll")                                                      \
        for (int i_ = 0; i_ < PF - 1; ++i_) { ap[i_] = ap[i_ + 1]; as[i_] = as[i_ + 1]; } \
        ap[PF - 1] = fp_; as[PF - 1] = fs_;                                    \
        px ^= 1;                                                               \
    }

    STEP(t0, false);                   // peeled (unabsorbed bias at true t=0)
    bpc = bpf; bsc = bsf;
#pragma unroll 2
    for (int t = t0 + 1; t <= tstart; ++t) STEP(t, false);
#pragma unroll 2
    for (int t = tstart + 1; t <= tstart + chunkSz; ++t) STEP(t, true);
#undef STEP
}

// ============================================================================
// Fallback (r9 kernel verbatim): used when ws_size can't hold even S=4 f16 Ax.
// ============================================================================
#define CHUNK_FB 256
__device__ __forceinline__ float gw_fb(const float* W_ih, const float* W_hh,
                                       const float* W_out, int r, int k) {
    if (k < NX) return W_ih[r * 20 + k];
    if (k >= 20 && k < 40)
        return fmaf(W_ih[r * 20 + 19], W_out[k - 20], W_hh[r * 20 + (k - 20)]);
    return 0.f;
}

__global__ __launch_bounds__(64, 2) void lstm_quad_kernel(
    const float* __restrict__ x, const float* __restrict__ W_ih,
    const float* __restrict__ W_hh, const float* __restrict__ b_ih,
    const float* __restrict__ b_hh, const float* __restrict__ W_out,
    const float* __restrict__ b_out, float* __restrict__ out)
{
    __shared__ __align__(16) float cls[2][48];
    __shared__ __align__(16) float gls[20][4];

    const int b  = blockIdx.x;
    const int ci = b / NGRID;
    const int g  = b - ci * NGRID;
    const int l  = threadIdx.x;
    const int qd = l >> 2;
    const int qi = l & 3;
    const int qb = 12 * qi;

    const int tstart = ci * CHUNK_FB;
    const int t0     = (ci == 0) ? 0 : tstart - WARM;

    const int g1 = l / HDIM;
    const int u1 = l % HDIM;
    const float bout = b_out[0];

    f2 w_own[20];
#pragma unroll
    for (int kk = 0; kk < 20; ++kk)
        w_own[kk] = f2{gw_fb(W_ih, W_hh, W_out, l, 2 * kk),
                       gw_fb(W_ih, W_hh, W_out, l, 2 * kk + 1)};
    const float bb1 = b_ih[l] + b_hh[l];
    const float b1f = fmaf(W_ih[l * 20 + 19], bout, bb1);
    float b1c = (ci == 0) ? bb1 : b1f;

    const int rs = 64 + qd;
    f2 w_sh[6];
#pragma unroll
    for (int m = 0; m < 6; ++m)
        w_sh[m] = f2{gw_fb(W_ih, W_hh, W_out, rs, qb + 2 * m),
                     gw_fb(W_ih, W_hh, W_out, rs, qb + 2 * m + 1)};
    const float bbs = b_ih[rs] + b_hh[rs];
    const float bsf = fmaf(W_ih[rs * 20 + 19], bout, bbs);
    float bsc = (ci == 0) ? bbs : bsf;

    f2 w_oq[6];
#pragma unroll
    for (int m = 0; m < 6; ++m) {
        const int k0 = qb + 2 * m, k1 = k0 + 1;
        w_oq[m] = f2{(k0 >= 20 && k0 < 40) ? W_out[k0 - 20] : 0.f,
                     (k1 >= 20 && k1 < 40) ? W_out[k1 - 20] : 0.f};
    }

    const float m1 = (g1 == 2) ? (2.f * L2E) : -L2E;
    const float A1 = (g1 == 2) ?  1.f :  0.f;
    const float B1 = (g1 == 2) ? -2.f :  1.f;

    const int    kl   = (l < NX) ? l : 0;
    const float* xptr = x + (size_t)g * NX + kl;
    const size_t tsx  = (size_t)NGRID * NX;
    float xr[PF];
#pragma unroll
    for (int p = 0; p < PF; ++p) {
        int tp = t0 + 1 + p; if (tp > NT - 1) tp = NT - 1;
        xr[p] = xptr[(size_t)tp * tsx];
    }
    if (l < 8)    { cls[0][40 + l] = 0.f; cls[1][40 + l] = 0.f; }
    if (l < HDIM) { cls[0][20 + l] = 0.f; cls[0][l] = xptr[(size_t)t0 * tsx]; }

    float  c  = 0.f;
    int    px = 0;
    float* op = out + (size_t)tstart * NGRID + g;

#define STEPF(T, DO_STORE)                                                     \
    {                                                                          \
        if (l < HDIM) cls[px ^ 1][l] = xr[0];                                  \
        int tf_ = (T) + 1 + PF; if (tf_ > NT - 1) tf_ = NT - 1;                \
        const float xf_ = xptr[(size_t)tf_ * tsx];                             \
        f2 aA = f2{b1c, 0.f}, aB = f2{0.f, 0.f};                               \
        _Pragma("unroll")                                                      \
        for (int ii = 0; ii < 10; ++ii) {                                      \
            const f4 X = ((const f4*)&cls[px][0])[ii];                         \
            pk_fma(aA, f2{X.x, X.y}, w_own[2 * ii]);                           \
            pk_fma(aB, f2{X.z, X.w}, w_own[2 * ii + 1]);                       \
        }                                                                      \
        const f4 Q0 = *(const f4*)&cls[px][qb];                                \
        const f4 Q1 = *(const f4*)&cls[px][qb + 4];                            \
        const f4 Q2 = *(const f4*)&cls[px][qb + 8];                            \
        f2 sS = f2{0.f, 0.f}, sO = f2{0.f, 0.f};                               \
        pk_fma(sS, f2{Q0.x, Q0.y}, w_sh[0]); pk_fma(sO, f2{Q0.x, Q0.y}, w_oq[0]); \
        pk_fma(sS, f2{Q0.z, Q0.w}, w_sh[1]); pk_fma(sO, f2{Q0.z, Q0.w}, w_oq[1]); \
        pk_fma(sS, f2{Q1.x, Q1.y}, w_sh[2]); pk_fma(sO, f2{Q1.x, Q1.y}, w_oq[2]); \
        pk_fma(sS, f2{Q1.z, Q1.w}, w_sh[3]); pk_fma(sO, f2{Q1.z, Q1.w}, w_oq[3]); \
        pk_fma(sS, f2{Q2.x, Q2.y}, w_sh[4]); pk_fma(sO, f2{Q2.x, Q2.y}, w_oq[4]); \
        pk_fma(sS, f2{Q2.z, Q2.w}, w_sh[5]); pk_fma(sO, f2{Q2.z, Q2.w}, w_oq[5]); \
        const float vs = quad_sum(sS.x + sS.y);                                \
        const float vo = quad_sum(sO.x + sO.y);                                \
        const float a1 = aA.x + aA.y + aB.x + aB.y;                            \
        const float e1 = EXP2(m1 * a1);                                        \
        gls[u1][g1] = fmaf(B1, frcp(1.f + e1), A1);                            \
        if (qi == 0) gls[4 + qd][3] = frcp(1.f + EXP2(-L2E * (vs + bsc)));     \
        if (DO_STORE) { if (l == 0) *op = vo + bout; op += NGRID; }            \
        asm volatile("s_waitcnt lgkmcnt(0)" ::: "memory");                     \
        if (l < HDIM) {                                                        \
            const f4 gv = *(const f4*)&gls[l][0];                              \
            c = fmaf(gv.y, c, gv.x * gv.z);                                    \
            const float ec = EXP2(2.f * L2E * c);                              \
            cls[px ^ 1][20 + l] = gv.w * (1.f - 2.f * frcp(1.f + ec));         \
        }                                                                      \
        _Pragma("unroll")                                                      \
        for (int i_ = 0; i_ < PF - 1; ++i_) xr[i_] = xr[i_ + 1];               \
        xr[PF - 1] = xf_;                                                      \
        px ^= 1;                                                               \
    }

    STEPF(t0, false);
    b1c = b1f; bsc = bsf;
#pragma unroll 2
    for (int t = t0 + 1; t <= tstart; ++t) STEPF(t, false);
#pragma unroll 2
    for (int t = tstart + 1; t <= tstart + CHUNK_FB; ++t) STEPF(t, true);
#undef STEPF
}

extern "C" void kernel_launch(void* const* d_in, const int* in_sizes, int n_in,
                              void* d_out, int out_size, void* d_ws, size_t ws_size,
                              hipStream_t stream) {
    const float* x     = (const float*)d_in[0];
    const float* W_ih  = (const float*)d_in[1];
    const float* W_hh  = (const float*)d_in[2];
    const float* b_ih  = (const float*)d_in[3];
    const float* b_hh  = (const float*)d_in[4];
    const float* W_out = (const float*)d_in[5];
    const float* b_out = (const float*)d_in[6];
    float* out = (float*)d_out;

    const size_t perT = (size_t)NGRID * 80 * sizeof(u16);   // 4480 B per t-slot
    int S = 0, chunk = 256;
    if      (ws_size >= (size_t)NT * perT)              { S = 1; chunk = 256; }  // 294 MB
    else if (ws_size >= (size_t)(NT / 2 + WARM) * perT) { S = 2; chunk = 256; }  // 147 MB
    else if (ws_size >= (size_t)(NT / 4 + WARM) * perT) { S = 4; chunk = 128; }  //  74 MB

    if (S) {
        u16* Aws = (u16*)d_ws;
        const int NTSEG = NT / S;
        for (int s = 0; s < S; ++s) {
            const int segT0   = s * NTSEG;
            const int segEnd  = segT0 + NTSEG;
            const int aw_base = (s == 0) ? 0 : segT0 - WARM;
            const int nt_cov  = segEnd - aw_base;
            ax_kernel<<<dim3(nt_cov * NGRID / TGB), dim3(320), 0, stream>>>(
                x, W_ih, Aws, aw_base);
            lstm_main_kernel<<<dim3((NTSEG / chunk) * NGRID), dim3(64), 0, stream>>>(
                Aws, W_ih, W_hh, b_ih, b_hh, W_out, b_out, out,
                segT0 / chunk, chunk, aw_base, segEnd - 1);
        }
    } else {
        lstm_quad_kernel<<<dim3((NT / CHUNK_FB) * NGRID), dim3(64), 0, stream>>>(
            x, W_ih, W_hh, b_ih, b_hh, W_out, b_out, out);
    }
}